// Round 3
// baseline (403.738 us; speedup 1.0000x reference)
//
#include <hip/hip_runtime.h>

#define BT 16384
#define DK 4096
#define NE 64
#define BM 64                 // rows per block; lane = row
#define KC 32                 // k floats per chunk (8 quads) -> W chunk 8KB/CU, K$-resident
#define NQ (KC / 4)           // 8 quads per row per chunk
#define NC (DK / KC)          // 128 chunks
#define NTHR 512              // 8 waves; wave wv owns experts [wv*8, wv*8+8)
#define NPROBS (BT * NE)
#define NIDX (NPROBS)
#define NWTS (NPROBS + BT * 2)

__global__ __launch_bounds__(NTHR) void token_router(
    const float* __restrict__ x, const float* __restrict__ W,
    float* __restrict__ out)
{
    __shared__ float4 xs4[2 * BM * NQ];   // 2 x 64 x 8 x 16B = 16 KB, double-buffered
    __shared__ float  lg[BM * 68];        // logits, padded stride
    __shared__ float  rowm[BM], rowinv[BM];

    const int tid  = threadIdx.x;
    const int lane = tid & 63;            // = row within block tile
    const long rowbase = (long)blockIdx.x * BM;

    // W base for this wave's 8 experts -- forced wave-uniform so the compiler
    // emits s_load (scalar pipe), keeping VMEM/DS free. All 8 waves stream the
    // same 8KB W chunk per barrier window -> K$-resident.
    const int woff = __builtin_amdgcn_readfirstlane((tid >> 6) * 8 * DK);
    const float* wp = W + woff;

    // ---- X staging: thread t stages slot (t&7) of row (t>>3), 1 float4/chunk.
    // LDS slot s of row r holds global quad (s ^ (r&7)) -> pre-swizzled source.
    const int srow = tid >> 3;
    const int ss   = tid & 7;
    const float* gx = x + (rowbase + srow) * (long)DK + ((ss ^ (srow & 7)) << 2);

    const int swz = lane & 7;

    float acc[8];
#pragma unroll
    for (int e = 0; e < 8; ++e) acc[e] = 0.f;

    // prologue: stage chunk 0 into buffer 0
    {
        float4 pa = *(const float4*)(gx);
        xs4[srow * NQ + ss] = pa;
    }
    __syncthreads();

    for (int c = 0; c < NC; ++c) {
        float4 pa;
        if (c + 1 < NC) pa = *(const float4*)(gx + (c + 1) * KC);  // prefetch next chunk

        // load this lane's row-slice of X for the chunk: 8 x ds_read_b128
        const int xb = (c & 1) * (BM * NQ) + lane * NQ;
        float4 xq[NQ];
#pragma unroll
        for (int q = 0; q < NQ; ++q)
            xq[q] = xs4[xb + (q ^ swz)];

        // 8 experts x 32 k FMAs; W quads per expert are 128B contiguous -> merged s_loads
#pragma unroll
        for (int e = 0; e < 8; ++e) {
            const float* we = wp + e * DK + c * KC;
            float a = acc[e];
#pragma unroll
            for (int q = 0; q < NQ; ++q) {
                const float4 w = *(const float4*)(we + q * 4);
                a = fmaf(xq[q].x, w.x, a);
                a = fmaf(xq[q].y, w.y, a);
                a = fmaf(xq[q].z, w.z, a);
                a = fmaf(xq[q].w, w.w, a);
            }
            acc[e] = a;
        }

        if (c + 1 < NC)
            xs4[((c + 1) & 1) * (BM * NQ) + srow * NQ + ss] = pa;  // write-late into other buffer
        __syncthreads();
    }

    // ---- logits to LDS: lane(=row) writes its wave's 8 expert columns ----
    {
        const int ebase = (tid >> 6) * 8;
#pragma unroll
        for (int e = 0; e < 8; ++e)
            lg[lane * 68 + ebase + e] = acc[e];
    }
    __syncthreads();

    // ---- per-row softmax stats + top-2 (one thread per row) ----
    if (tid < BM) {
        const int row = tid;
        float m = -3.4e38f;
        for (int e = 0; e < NE; ++e) m = fmaxf(m, lg[row * 68 + e]);
        float s = 0.f;
        float v1 = -1.f, v2 = -1.f;
        int   i1 = 0,    i2 = 0;
        for (int e = 0; e < NE; ++e) {
            float p = __expf(lg[row * 68 + e] - m);
            s += p;
            if (p > v1)      { v2 = v1; i2 = i1; v1 = p; i1 = e; }
            else if (p > v2) { v2 = p; i2 = e; }
        }
        const float inv = 1.f / s;
        rowm[row]   = m;
        rowinv[row] = inv;
        const long grow = rowbase + row;
        const float p1 = v1 * inv, p2 = v2 * inv;
        const float dn = p1 + p2 + 1e-9f;
        out[NIDX + grow * 2 + 0] = (float)i1;
        out[NIDX + grow * 2 + 1] = (float)i2;
        out[NWTS + grow * 2 + 0] = p1 / dn;
        out[NWTS + grow * 2 + 1] = p2 / dn;
    }
    __syncthreads();

    // ---- probs write: 512 threads x 8 floats (2 float4), fully coalesced ----
    {
        const int row = tid >> 3;
        const int e0  = (tid & 7) << 3;
        const float m = rowm[row], inv = rowinv[row];
        const long grow = rowbase + row;
        float4 l4a = *reinterpret_cast<const float4*>(&lg[row * 68 + e0]);
        float4 l4b = *reinterpret_cast<const float4*>(&lg[row * 68 + e0 + 4]);
        float4 p0, p1;
        p0.x = __expf(l4a.x - m) * inv;
        p0.y = __expf(l4a.y - m) * inv;
        p0.z = __expf(l4a.z - m) * inv;
        p0.w = __expf(l4a.w - m) * inv;
        p1.x = __expf(l4b.x - m) * inv;
        p1.y = __expf(l4b.y - m) * inv;
        p1.z = __expf(l4b.z - m) * inv;
        p1.w = __expf(l4b.w - m) * inv;
        *reinterpret_cast<float4*>(&out[grow * (long)NE + e0])     = p0;
        *reinterpret_cast<float4*>(&out[grow * (long)NE + e0 + 4]) = p1;
    }
}

extern "C" void kernel_launch(void* const* d_in, const int* in_sizes, int n_in,
                              void* d_out, int out_size, void* d_ws, size_t ws_size,
                              hipStream_t stream) {
    const float* x = (const float*)d_in[0];
    const float* W = (const float*)d_in[1];
    float* out = (float*)d_out;
    dim3 grid(BT / BM);   // 256 blocks, 1 per CU
    dim3 block(NTHR);     // 512 threads = 8 waves
    token_router<<<grid, block, 0, stream>>>(x, W, out);
}